// Round 5
// baseline (215.933 us; speedup 1.0000x reference)
//
#include <hip/hip_runtime.h>
#include <cmath>

// Problem constants: B=32768, N=17, D=2, K=3, H=64 (bMLP hidden=128, out=12)
#define NBATCH 32768
#define NJOINT 17
#define OUT0_ELEMS (NBATCH * NJOINT * 15)          // out[B,N,3,5]
#define KJS_OFF    OUT0_ELEMS                      // k_js[B,N]
#define MASK_OFF   (KJS_OFF + NBATCH * NJOINT)     // mask[B,N,3]
#define NPT 4                                      // points per thread

__device__ __forceinline__ float sel3f(int i, float a, float b, float c) {
    return (i == 0) ? a : ((i == 1) ? b : c);
}

// Cold path: exact fp64 recompute of a 2->64->3 MLP (uniform s_load weights).
// Taken only when fp32 logits have a near-tie (< 1e-4 rel) that could flip
// the discrete argmax / argsort decisions (trigger ~0.1% of lanes).
__device__ __noinline__ void mlp64_small(
    const float* __restrict__ W1a, const float* __restrict__ W1b,
    const float* __restrict__ b1,  const float* __restrict__ W2,
    const float* __restrict__ b2,
    double x0, double x1, double& l0, double& l1, double& l2)
{
    l0 = (double)b2[0]; l1 = (double)b2[1]; l2 = (double)b2[2];
    for (int h = 0; h < 64; ++h) {
        double hv = fma(x1, (double)W1b[h], fma(x0, (double)W1a[h], (double)b1[h]));
        hv = fmax(hv, 0.0);
        l0 = fma(hv, (double)W2[h * 3 + 0], l0);
        l1 = fma(hv, (double)W2[h * 3 + 1], l1);
        l2 = fma(hv, (double)W2[h * 3 + 2], l2);
    }
}

// Per-point epilogue: tie-checks + argmax/argsort + softmax + exp + writes.
__device__ __forceinline__ void finish_point(
    float x0f, float x1f,
    float kf0, float kf1, float kf2,
    float wf0, float wf1, float wf2,
    const float* acc,      // 12 bMLP outputs (bb2 already added)
    int n, int p,
    const float* __restrict__ kW1, const float* __restrict__ kb1,
    const float* __restrict__ kW2, const float* __restrict__ kb2,
    const float* __restrict__ wW1, const float* __restrict__ wb1,
    const float* __restrict__ wW2, const float* __restrict__ wb2,
    float* __restrict__ out)
{
    // k argmax with fp64 fallback on near-tie
    double kl0 = (double)kf0, kl1 = (double)kf1, kl2 = (double)kf2;
    {
        const float d01 = fabsf(kf0 - kf1), d02 = fabsf(kf0 - kf2), d12 = fabsf(kf1 - kf2);
        const float sc = fmaxf(fmaxf(fabsf(kf0), fabsf(kf1)), fabsf(kf2));
        if (fminf(fminf(d01, d02), d12) < 1e-4f * fmaxf(sc, 1.0f))
            mlp64_small(kW1 + n * 128, kW1 + n * 128 + 64, kb1 + n * 64,
                        kW2 + n * 192, kb2 + n * 3,
                        (double)x0f, (double)x1f, kl0, kl1, kl2);
    }
    int kj = 0;  // first-occurrence argmax (jnp.argmax semantics)
    {
        double m = kl0;
        if (kl1 > m) { m = kl1; kj = 1; }
        if (kl2 > m) { kj = 2; }
    }

    // w argsort with fp64 fallback on near-tie
    double wl0 = (double)wf0, wl1 = (double)wf1, wl2 = (double)wf2;
    {
        const float d01 = fabsf(wf0 - wf1), d02 = fabsf(wf0 - wf2), d12 = fabsf(wf1 - wf2);
        const float sc = fmaxf(fmaxf(fabsf(wf0), fabsf(wf1)), fabsf(wf2));
        if (fminf(fminf(d01, d02), d12) < 1e-4f * fmaxf(sc, 1.0f))
            mlp64_small(wW1 + n * 128, wW1 + n * 128 + 64, wb1 + n * 64,
                        wW2 + n * 192, wb2 + n * 3,
                        (double)x0f, (double)x1f, wl0, wl1, wl2);
    }
    // stable descending argsort of 3 (jnp.argsort(-w): ties -> lower index first)
    int i0 = 0;
    {
        double m = wl0;
        if (wl1 > m) { m = wl1; i0 = 1; }
        if (wl2 > m) { i0 = 2; }
    }
    const int ia = (i0 == 0) ? 1 : 0;
    const int ib = (i0 == 2) ? 1 : 2;
    const double wa = ia ? wl1 : wl0;
    const double wb = (ib == 1) ? wl1 : wl2;
    const int i1 = (wb > wa) ? ib : ia;
    const int i2 = (wb > wa) ? ia : ib;

    // softmax from fp32 logits (2% tolerance; fp32 error ~1e-6)
    const float mw = fmaxf(fmaxf(wf0, wf1), wf2);
    const float e0 = __expf(wf0 - mw);
    const float e1 = __expf(wf1 - mw);
    const float e2 = __expf(wf2 - mw);
    const float inv = 1.0f / (e0 + e1 + e2);
    const float p0 = e0 * inv, p1 = e1 * inv, p2 = e2 * inv;

    float r[15];
    r[0]  = p0; r[5] = p1; r[10] = p2;
    r[1]  = sel3f(i0, acc[0], acc[4], acc[8]);
    r[2]  = sel3f(i0, acc[1], acc[5], acc[9]);
    r[3]  = __expf(sel3f(i0, acc[2], acc[6], acc[10]));
    r[4]  = __expf(sel3f(i0, acc[3], acc[7], acc[11]));
    r[6]  = sel3f(i1, acc[0], acc[4], acc[8]);
    r[7]  = sel3f(i1, acc[1], acc[5], acc[9]);
    r[8]  = __expf(sel3f(i1, acc[2], acc[6], acc[10]));
    r[9]  = __expf(sel3f(i1, acc[3], acc[7], acc[11]));
    r[11] = sel3f(i2, acc[0], acc[4], acc[8]);
    r[12] = sel3f(i2, acc[1], acc[5], acc[9]);
    r[13] = __expf(sel3f(i2, acc[2], acc[6], acc[10]));
    r[14] = __expf(sel3f(i2, acc[3], acc[7], acc[11]));

    float* o = out + (size_t)p * 15;
    #pragma unroll
    for (int i = 0; i < 15; ++i) o[i] = r[i];

    out[KJS_OFF + p] = (float)(kj + 1);

    float* mk = out + MASK_OFF + (size_t)p * 3;
    mk[0] = 1.0f;
    mk[1] = (kj >= 1) ? 1.0f : 0.0f;
    mk[2] = (kj >= 2) ? 1.0f : 0.0f;
}

// NPT points per thread: each s_load wait window now covers NPT x the FMA
// work, so ~2 resident waves/SIMD suffice to hide the ~400-cyc scalar-fetch
// latency that dominated rounds 1-4. Weights stay wave-uniform (n=blockIdx.y).
__global__ __launch_bounds__(256) void mdn_fused(
    const float* __restrict__ pred_pts,
    const float* __restrict__ kW1, const float* __restrict__ kb1,
    const float* __restrict__ kW2, const float* __restrict__ kb2,
    const float* __restrict__ wW1, const float* __restrict__ wb1,
    const float* __restrict__ wW2, const float* __restrict__ wb2,
    const float* __restrict__ bW1, const float* __restrict__ bb1,
    const float* __restrict__ bW2, const float* __restrict__ bb2,
    float* __restrict__ out)
{
    const int n = blockIdx.y;
    const int t = threadIdx.x;
    const int b0 = blockIdx.x * (256 * NPT) + t;

    int   pp[NPT];
    float x0[NPT], x1[NPT];
    #pragma unroll
    for (int i = 0; i < NPT; ++i) {
        const int b = b0 + i * 256;
        pp[i] = b * NJOINT + n;
        const float2 xv = *reinterpret_cast<const float2*>(pred_pts + 2 * pp[i]);
        x0[i] = xv.x; x1[i] = xv.y;
    }

    // ---------------- kMLP : 2 -> 64 -> 3, fp32, NPT points ----------------
    const float* kW1a = kW1 + n * 128;
    const float* kW1b = kW1a + 64;
    const float* kb1p = kb1 + n * 64;
    const float* kW2p = kW2 + n * 192;
    float kf[NPT][3];
    #pragma unroll
    for (int i = 0; i < NPT; ++i) {
        kf[i][0] = kb2[n * 3 + 0]; kf[i][1] = kb2[n * 3 + 1]; kf[i][2] = kb2[n * 3 + 2];
    }
    #pragma unroll 8
    for (int h = 0; h < 64; ++h) {
        const float wa = kW1a[h], wb = kW1b[h], bb = kb1p[h];
        const float w20 = kW2p[h * 3 + 0], w21 = kW2p[h * 3 + 1], w22 = kW2p[h * 3 + 2];
        #pragma unroll
        for (int i = 0; i < NPT; ++i) {
            const float hv = fmaxf(fmaf(x1[i], wb, fmaf(x0[i], wa, bb)), 0.0f);
            kf[i][0] = fmaf(hv, w20, kf[i][0]);
            kf[i][1] = fmaf(hv, w21, kf[i][1]);
            kf[i][2] = fmaf(hv, w22, kf[i][2]);
        }
    }

    // ---------------- wMLP : 2 -> 64 -> 3, fp32, NPT points ----------------
    const float* wW1a = wW1 + n * 128;
    const float* wW1b = wW1a + 64;
    const float* wb1p = wb1 + n * 64;
    const float* wW2p = wW2 + n * 192;
    float wf[NPT][3];
    #pragma unroll
    for (int i = 0; i < NPT; ++i) {
        wf[i][0] = wb2[n * 3 + 0]; wf[i][1] = wb2[n * 3 + 1]; wf[i][2] = wb2[n * 3 + 2];
    }
    #pragma unroll 8
    for (int h = 0; h < 64; ++h) {
        const float wa = wW1a[h], wb = wW1b[h], bb = wb1p[h];
        const float w20 = wW2p[h * 3 + 0], w21 = wW2p[h * 3 + 1], w22 = wW2p[h * 3 + 2];
        #pragma unroll
        for (int i = 0; i < NPT; ++i) {
            const float hv = fmaxf(fmaf(x1[i], wb, fmaf(x0[i], wa, bb)), 0.0f);
            wf[i][0] = fmaf(hv, w20, wf[i][0]);
            wf[i][1] = fmaf(hv, w21, wf[i][1]);
            wf[i][2] = fmaf(hv, w22, wf[i][2]);
        }
    }

    // ---------------- bMLP : 2 -> 128 -> 12, fp32, NPT points --------------
    float acc[NPT][12];
    {
        const float* W1a = bW1 + n * 256;
        const float* W1b = W1a + 128;
        const float* b1  = bb1 + n * 128;
        const float* W2  = bW2 + n * 1536;
        const float* b2  = bb2 + n * 12;
        #pragma unroll
        for (int i = 0; i < NPT; ++i)
            #pragma unroll
            for (int j = 0; j < 12; ++j) acc[i][j] = b2[j];
        #pragma unroll 4
        for (int h = 0; h < 128; ++h) {
            const float wa = W1a[h], wb = W1b[h], bb = b1[h];
            float w2r[12];
            #pragma unroll
            for (int j = 0; j < 12; ++j) w2r[j] = W2[h * 12 + j];
            #pragma unroll
            for (int i = 0; i < NPT; ++i) {
                const float hv = fmaxf(fmaf(x1[i], wb, fmaf(x0[i], wa, bb)), 0.0f);
                #pragma unroll
                for (int j = 0; j < 12; ++j)
                    acc[i][j] = fmaf(hv, w2r[j], acc[i][j]);
            }
        }
    }

    // ---------------- epilogue (per point) ---------------------------------
    #pragma unroll
    for (int i = 0; i < NPT; ++i)
        finish_point(x0[i], x1[i],
                     kf[i][0], kf[i][1], kf[i][2],
                     wf[i][0], wf[i][1], wf[i][2],
                     acc[i], n, pp[i],
                     kW1, kb1, kW2, kb2, wW1, wb1, wW2, wb2, out);
}

extern "C" void kernel_launch(void* const* d_in, const int* in_sizes, int n_in,
                              void* d_out, int out_size, void* d_ws, size_t ws_size,
                              hipStream_t stream) {
    (void)in_sizes; (void)n_in; (void)d_ws; (void)ws_size; (void)out_size;
    dim3 grid(NBATCH / (256 * NPT), NJOINT);
    mdn_fused<<<grid, 256, 0, stream>>>(
        (const float*)d_in[0],
        (const float*)d_in[1], (const float*)d_in[2],
        (const float*)d_in[3], (const float*)d_in[4],
        (const float*)d_in[5], (const float*)d_in[6],
        (const float*)d_in[7], (const float*)d_in[8],
        (const float*)d_in[9], (const float*)d_in[10],
        (const float*)d_in[11], (const float*)d_in[12],
        (float*)d_out);
}